// Round 1
// baseline (451.438 us; speedup 1.0000x reference)
//
#include <hip/hip_runtime.h>
#include <stdint.h>

#define B_DIM 256
#define S_DIM 16384
#define F_DIM 16
#define D_DIM 113          // 7*16+1

#define NTHREADS 256
#define PER_TH 64          // S_DIM / NTHREADS
#define HBITS 13
#define NBINS (1 << HBITS) // 8192
#define HSHIFT (32 - HBITS)
#define SEG 340            // candidate cap per rank-task
#define KEYINF 0xFF800000u

__device__ __forceinline__ uint32_t enc_key(float v) {
    uint32_t u = __float_as_uint(v);
    uint32_t m = (uint32_t)((int32_t)u >> 31) | 0x80000000u;
    return u ^ m;
}
__device__ __forceinline__ float dec_key(uint32_t k) {
    uint32_t u = (k & 0x80000000u) ? (k ^ 0x80000000u) : ~k;
    return __uint_as_float(u);
}
__device__ __forceinline__ uint32_t umn(uint32_t a, uint32_t b) { return a < b ? a : b; }
__device__ __forceinline__ uint32_t umx(uint32_t a, uint32_t b) { return a > b ? a : b; }

// ---------------------------------------------------------------------------
// Detect mask element width: bool(1B) vs int32(4B). For int32 0/1 values every
// byte at (idx & 3) != 0 is zero; for random bool bytes they are not.
// flag = 1 -> 1-byte elements, flag = 0 -> 4-byte elements.
// ---------------------------------------------------------------------------
__global__ void detect_mask_kernel(const unsigned char* __restrict__ mb,
                                   unsigned int* __restrict__ flag) {
    __shared__ unsigned int acc[256];
    int t = threadIdx.x;
    unsigned int x = 0;
    for (int i = 0; i < 256; ++i) {
        int idx = t * 256 + i;          // bytes 0..65535 (buffer >= 4 MiB either way)
        if ((idx & 3) != 0) x |= mb[idx];
    }
    acc[t] = x;
    __syncthreads();
    for (int off = 128; off; off >>= 1) {
        if (t < off) acc[t] |= acc[t + off];
        __syncthreads();
    }
    if (t == 0) *flag = (acc[0] != 0) ? 1u : 0u;
}

// ---------------------------------------------------------------------------
// Transpose [B,S,F] -> [B,F,S], encoding masked-out entries as +inf.
// ---------------------------------------------------------------------------
__global__ __launch_bounds__(256) void transpose_kernel(
        const float* __restrict__ in, const unsigned char* __restrict__ mb,
        const unsigned int* __restrict__ flag, float* __restrict__ T) {
    int t = threadIdx.x;
    int b = blockIdx.x >> 6;
    int s0 = (blockIdx.x & 63) << 8;   // 64 chunks of 256 rows

    __shared__ float tile[256][17];    // +1 pad: conflict-free column reads

    const float4* in4 = reinterpret_cast<const float4*>(
        in + ((size_t)b * S_DIM + (size_t)s0) * F_DIM);
    #pragma unroll
    for (int i = 0; i < 4; ++i) {
        int idx = i * 256 + t;         // 1024 float4 = 256 rows x 16 feats
        float4 v = in4[idx];
        int sl = idx >> 2, fg = (idx & 3) * 4;
        tile[sl][fg + 0] = v.x;
        tile[sl][fg + 1] = v.y;
        tile[sl][fg + 2] = v.z;
        tile[sl][fg + 3] = v.w;
    }
    __syncthreads();

    size_t mstride = (*flag) ? (size_t)1 : (size_t)4;
    unsigned char m = mb[((size_t)b * S_DIM + (size_t)(s0 + t)) * mstride];
    float INFV = __uint_as_float(0x7F800000u);
    size_t obase = ((size_t)b * F_DIM) * S_DIM + (size_t)(s0 + t);
    #pragma unroll
    for (int f2 = 0; f2 < 16; ++f2)
        T[obase + (size_t)f2 * S_DIM] = m ? tile[t][f2] : INFV;
}

// ---------------------------------------------------------------------------
// Per-(b,f) stats: count/sum/sumsq/min/max + exact rank selection for the
// 6 order-statistic ranks (lo/hi of q25/q50/q75).
// ---------------------------------------------------------------------------
__global__ __launch_bounds__(256) void stats_kernel(
        const float* __restrict__ tsrc, const float* __restrict__ in,
        const unsigned char* __restrict__ mb, const unsigned int* __restrict__ flag,
        int direct, float* __restrict__ pooled) {
    int t = threadIdx.x;
    int blk = blockIdx.x;
    int b = blk >> 4, f = blk & 15;

    __shared__ uint32_t hist[NBINS];
    __shared__ uint32_t cand[6 * SEG];
    __shared__ uint32_t redu[256];
    __shared__ float s_f[16];
    __shared__ uint32_t s_u[16];
    __shared__ uint32_t sh_bucket[6], sh_rib[6], sh_ccnt[6], sh_res[6];

    uint32_t k[PER_TH];
    float sum = 0.f, sumsq = 0.f;
    uint32_t mn = 0xFFFFFFFFu, mx = 0u;
    int cnt = 0;
    float INFV = __uint_as_float(0x7F800000u);

    auto proc = [&](float v) -> uint32_t {
        uint32_t key = enc_key(v);
        if (key < KEYINF) {
            sum += v;
            sumsq += v * v;
            ++cnt;
            mn = umn(mn, key);
            mx = umx(mx, key);
        } else {
            key = KEYINF;
        }
        return key;
    };

    if (!direct) {
        const float4* src4 = reinterpret_cast<const float4*>(tsrc + (size_t)blk * S_DIM);
        #pragma unroll
        for (int i = 0; i < 16; ++i) {
            float4 v = src4[i * 256 + t];
            k[4 * i + 0] = proc(v.x);
            k[4 * i + 1] = proc(v.y);
            k[4 * i + 2] = proc(v.z);
            k[4 * i + 3] = proc(v.w);
        }
    } else {
        const float* base = in + (size_t)b * S_DIM * F_DIM + f;
        size_t mstride = (*flag) ? (size_t)1 : (size_t)4;
        const unsigned char* mrow = mb + (size_t)b * S_DIM * mstride;
        #pragma unroll
        for (int j = 0; j < PER_TH; ++j) {
            int s = j * 256 + t;
            float v = base[(size_t)s * F_DIM];
            unsigned char m = mrow[(size_t)s * mstride];
            k[j] = proc(m ? v : INFV);
        }
    }

    // block reduction: wave shuffle then cross-wave via LDS
    #pragma unroll
    for (int off = 32; off; off >>= 1) {
        sum += __shfl_down(sum, off);
        sumsq += __shfl_down(sumsq, off);
        cnt += __shfl_down(cnt, off);
        mn = umn(mn, (uint32_t)__shfl_down((int)mn, off));
        mx = umx(mx, (uint32_t)__shfl_down((int)mx, off));
    }
    int wv = t >> 6;
    if ((t & 63) == 0) {
        s_f[wv] = sum; s_f[4 + wv] = sumsq;
        s_u[wv] = (uint32_t)cnt; s_u[4 + wv] = mn; s_u[8 + wv] = mx;
    }
    __syncthreads();
    if (t == 0) {
        float ts = 0.f, tq = 0.f;
        uint32_t tc = 0, tmn = 0xFFFFFFFFu, tmx = 0;
        for (int w = 0; w < 4; ++w) {
            ts += s_f[w]; tq += s_f[4 + w];
            tc += s_u[w]; tmn = umn(tmn, s_u[4 + w]); tmx = umx(tmx, s_u[8 + w]);
        }
        s_f[8] = ts; s_f[9] = tq;
        s_u[12] = tc; s_u[13] = tmn; s_u[14] = tmx;
    }
    __syncthreads();
    float tot_sum = s_f[8], tot_ssq = s_f[9];
    int n = (int)s_u[12];
    uint32_t key_mn = s_u[13], key_mx = s_u[14];

    if (n == 0) {  // empty batch -> all-zero stats (uniform early return)
        if (t == 0) {
            float* pb = pooled + (size_t)b * D_DIM;
            if (f == 0) pb[0] = 0.f;
            pb[1 + f] = 0.f; pb[17 + f] = 0.f; pb[33 + f] = 0.f; pb[49 + f] = 0.f;
            pb[65 + f] = 0.f; pb[81 + f] = 0.f; pb[97 + f] = 0.f;
        }
        return;
    }

    // 8192-bin histogram over top 13 bits of sortable key (finite only)
    for (int i = t; i < NBINS; i += 256) hist[i] = 0u;
    __syncthreads();
    #pragma unroll
    for (int j = 0; j < PER_TH; ++j)
        if (k[j] < KEYINF) atomicAdd(&hist[k[j] >> HSHIFT], 1u);
    __syncthreads();

    // per-thread partials (32 bins each) + Hillis-Steele inclusive scan
    {
        uint32_t p = 0;
        int bb = t * (NBINS / 256);
        for (int i = 0; i < NBINS / 256; ++i) p += hist[bb + i];
        redu[t] = p;
    }
    __syncthreads();
    for (int off = 1; off < 256; off <<= 1) {
        uint32_t add = (t >= off) ? redu[t - off] : 0u;
        __syncthreads();
        redu[t] += add;
        __syncthreads();
    }

    // 6 rank tasks: t in [0,6) handles (q = t>>1, lo/hi by t&1)
    if (t < 6) {
        int q = t >> 1;
        float pos = 0.25f * (float)(q + 1) * (float)(n - 1);
        int lov = (int)floorf(pos);
        int r = (t & 1) ? (int)ceilf(pos) : lov;
        int a = 0, bnd = 255;  // first block with inclusive-sum > r
        while (a < bnd) {
            int mid = (a + bnd) >> 1;
            if (redu[mid] > (uint32_t)r) bnd = mid; else a = mid + 1;
        }
        uint32_t acc = (a > 0) ? redu[a - 1] : 0u;
        int bin = a * (NBINS / 256);
        while (true) {
            uint32_t h = hist[bin];
            if (acc + h > (uint32_t)r) break;
            acc += h;
            ++bin;
        }
        sh_bucket[t] = (uint32_t)bin;
        sh_rib[t] = (uint32_t)r - acc;
        sh_ccnt[t] = 0u;
    }
    __syncthreads();

    // compact candidates per rank-task (buckets may repeat; segments independent)
    {
        uint32_t bk0 = sh_bucket[0], bk1 = sh_bucket[1], bk2 = sh_bucket[2];
        uint32_t bk3 = sh_bucket[3], bk4 = sh_bucket[4], bk5 = sh_bucket[5];
        #pragma unroll
        for (int j = 0; j < PER_TH; ++j) {
            uint32_t key = k[j];
            if (key >= KEYINF) continue;
            uint32_t bin = key >> HSHIFT;
            if (bin == bk0) { uint32_t p = atomicAdd(&sh_ccnt[0], 1u); if (p < SEG) cand[0 * SEG + p] = key; }
            if (bin == bk1) { uint32_t p = atomicAdd(&sh_ccnt[1], 1u); if (p < SEG) cand[1 * SEG + p] = key; }
            if (bin == bk2) { uint32_t p = atomicAdd(&sh_ccnt[2], 1u); if (p < SEG) cand[2 * SEG + p] = key; }
            if (bin == bk3) { uint32_t p = atomicAdd(&sh_ccnt[3], 1u); if (p < SEG) cand[3 * SEG + p] = key; }
            if (bin == bk4) { uint32_t p = atomicAdd(&sh_ccnt[4], 1u); if (p < SEG) cand[4 * SEG + p] = key; }
            if (bin == bk5) { uint32_t p = atomicAdd(&sh_ccnt[5], 1u); if (p < SEG) cand[5 * SEG + p] = key; }
        }
    }
    __syncthreads();

    // exact rank-count within each segment (ties broken by index)
    for (int i = 0; i < 6; ++i) {
        uint32_t sz = umn(sh_ccnt[i], (uint32_t)SEG);
        const int base = i * SEG;
        int j1 = 256 + t;
        uint32_t k0 = (t < (int)sz) ? cand[base + t] : 0u;
        uint32_t k1 = (j1 < (int)sz) ? cand[base + j1] : 0u;
        uint32_t l0 = 0, l1 = 0;
        for (int c = 0; c < (int)sz; ++c) {
            uint32_t kc = cand[base + c];
            l0 += (kc < k0 || (kc == k0 && c < t)) ? 1u : 0u;
            l1 += (kc < k1 || (kc == k1 && c < j1)) ? 1u : 0u;
        }
        uint32_t rib = sh_rib[i];
        if (t < (int)sz && l0 == rib) sh_res[i] = k0;
        if (j1 < (int)sz && l1 == rib) sh_res[i] = k1;
    }
    __syncthreads();

    if (t == 0) {
        float safe = (float)n;
        float mean = tot_sum / safe;
        float varn = tot_ssq - tot_sum * tot_sum / safe;
        float denom = (float)((n - 1) > 1 ? (n - 1) : 1);
        float stdv = sqrtf(fmaxf(varn, 0.f) / denom);
        float qv[3];
        #pragma unroll
        for (int q = 0; q < 3; ++q) {
            float pos = 0.25f * (float)(q + 1) * (float)(n - 1);
            float frac = pos - floorf(pos);
            float lov = dec_key(sh_res[2 * q]);
            float hiv = dec_key(sh_res[2 * q + 1]);
            qv[q] = lov * (1.f - frac) + hiv * frac;
        }
        float* pb = pooled + (size_t)b * D_DIM;
        if (f == 0) pb[0] = (float)n;
        pb[1 + f] = mean;
        pb[17 + f] = qv[1];
        pb[33 + f] = dec_key(key_mn);
        pb[49 + f] = dec_key(key_mx);
        pb[65 + f] = stdv;
        pb[81 + f] = qv[0];
        pb[97 + f] = qv[2];
    }
}

// ---------------------------------------------------------------------------
// MLP: 113 -> 16 -> 4 -> 1, one block (1 wave) per batch row.
// ---------------------------------------------------------------------------
__global__ __launch_bounds__(64) void mlp_kernel(
        const float* __restrict__ pooled,
        const float* __restrict__ W1, const float* __restrict__ b1,
        const float* __restrict__ W2, const float* __restrict__ b2,
        const float* __restrict__ W3, const float* __restrict__ b3,
        float* __restrict__ out) {
    int b = blockIdx.x;
    int lane = threadIdx.x;
    const float* p = pooled + (size_t)b * D_DIM;
    float h = (lane < 16) ? b1[lane] : 0.f;
    for (int i = 0; i < D_DIM; ++i) {
        float pv = p[i];
        if (lane < 16) h += pv * W1[i * 16 + lane];
    }
    if (lane < 16) h = fmaxf(h, 0.f);
    float h2 = (lane < 4) ? b2[lane] : 0.f;
    for (int j = 0; j < 16; ++j) {
        float hj = __shfl(h, j);
        if (lane < 4) h2 += hj * W2[j * 4 + lane];
    }
    if (lane < 4) h2 = fmaxf(h2, 0.f);
    float o = 0.f;
    for (int j = 0; j < 4; ++j) {
        float hj = __shfl(h2, j);
        o += hj * W3[j];
    }
    if (lane == 0) out[b] = o + b3[0];
}

extern "C" void kernel_launch(void* const* d_in, const int* in_sizes, int n_in,
                              void* d_out, int out_size, void* d_ws, size_t ws_size,
                              hipStream_t stream) {
    const float* inputs = (const float*)d_in[0];
    const unsigned char* mask = (const unsigned char*)d_in[1];
    const float* W1 = (const float*)d_in[2];
    const float* b1 = (const float*)d_in[3];
    const float* W2 = (const float*)d_in[4];
    const float* b2 = (const float*)d_in[5];
    const float* W3 = (const float*)d_in[6];
    const float* b3 = (const float*)d_in[7];
    float* out = (float*)d_out;

    float* pooled = (float*)d_ws;                                  // 256*113*4 B
    unsigned int* flag = (unsigned int*)((char*)d_ws + 115712);
    float* T = (float*)((char*)d_ws + ((size_t)1 << 20));
    size_t Tbytes = (size_t)B_DIM * F_DIM * S_DIM * 4;             // 256 MiB
    bool useT = ws_size >= (((size_t)1 << 20) + Tbytes);

    detect_mask_kernel<<<1, 256, 0, stream>>>(mask, flag);
    if (useT) {
        transpose_kernel<<<B_DIM * 64, 256, 0, stream>>>(inputs, mask, flag, T);
        stats_kernel<<<B_DIM * F_DIM, 256, 0, stream>>>(T, nullptr, nullptr, flag, 0, pooled);
    } else {
        stats_kernel<<<B_DIM * F_DIM, 256, 0, stream>>>(nullptr, inputs, mask, flag, 1, pooled);
    }
    mlp_kernel<<<B_DIM, 64, 0, stream>>>(pooled, W1, b1, W2, b2, W3, b3, out);
}

// Round 2
// 282.967 us; speedup vs baseline: 1.5954x; 1.5954x over previous
//
#include <hip/hip_runtime.h>
#include <stdint.h>

#define B_DIM 256
#define S_DIM 16384
#define F_DIM 16
#define D_DIM 113          // 7*16+1

#define NTH 512
#define NF 8               // features per block (2 blocks per batch row)
#define NIT 64             // float4 iterations per thread
#define L1BINS 1024        // 10-bit level-1 histogram per feature
#define L2BINS 128         // 7-bit level-2 refinement
#define CAP 32             // candidate cap per 17-bit prefix
#define NTASK 48           // NF * 6 rank tasks

__device__ __forceinline__ uint32_t enc_key(float v) {
    uint32_t u = __float_as_uint(v);
    uint32_t m = (uint32_t)((int32_t)u >> 31) | 0x80000000u;
    return u ^ m;
}
__device__ __forceinline__ float dec_key(uint32_t k) {
    uint32_t u = (k & 0x80000000u) ? (k ^ 0x80000000u) : ~k;
    return __uint_as_float(u);
}
__device__ __forceinline__ uint32_t umn(uint32_t a, uint32_t b) { return a < b ? a : b; }
__device__ __forceinline__ uint32_t umx(uint32_t a, uint32_t b) { return a > b ? a : b; }

// ---------------------------------------------------------------------------
// Detect mask element width: bool(1B) vs int32(4B). For int32 0/1 values every
// byte at (idx & 3) != 0 is zero; random bool bytes are not all zero.
// flag = 1 -> 1-byte elements, flag = 0 -> 4-byte elements.
// ---------------------------------------------------------------------------
__global__ void detect_mask_kernel(const unsigned char* __restrict__ mb,
                                   unsigned int* __restrict__ flag) {
    __shared__ unsigned int acc[256];
    int t = threadIdx.x;
    unsigned int x = 0;
    for (int i = 0; i < 256; ++i) {
        int idx = t * 256 + i;
        if ((idx & 3) != 0) x |= mb[idx];
    }
    acc[t] = x;
    __syncthreads();
    for (int off = 128; off; off >>= 1) {
        if (t < off) acc[t] |= acc[t + off];
        __syncthreads();
    }
    if (t == 0) *flag = (acc[0] != 0) ? 1u : 0u;
}

// ---------------------------------------------------------------------------
// Fused stats kernel: block = (b, half). 3 streaming passes over the block's
// slice of the ORIGINAL layout (no transpose):
//   pass0: count/sum/sumsq/min/max + 10-bit L1 histogram (per feature)
//   rescan1: 7-bit L2 histogram restricted to the <=6 quantile buckets/feature
//   rescan2: compact candidates per 17-bit prefix (expected ~5, cap 32)
// then a trivial rank-count over the candidates. Masked elements encode as
// +inf keys (bin 1022) which can never match a valid rank bucket (<=1021).
// ---------------------------------------------------------------------------
__global__ __launch_bounds__(NTH, 4) void stats_kernel(
        const float* __restrict__ in, const unsigned char* __restrict__ mb,
        const unsigned int* __restrict__ flag, float* __restrict__ pooled) {
    __shared__ uint32_t uni[8192];           // 32KB union: hist[8][1024] -> hist2[48][128](24KB) + cand[48][32]@6144
    __shared__ uint32_t chunks[NF][64];
    __shared__ float p_sum[8][NF], p_ssq[8][NF];
    __shared__ uint32_t p_kmin[8][NF], p_kmax[8][NF];
    __shared__ uint32_t p_cnt[8];
    __shared__ float s_sum[NF], s_ssq[NF];
    __shared__ uint32_t s_kmin[NF], s_kmax[NF];
    __shared__ uint32_t s_n;
    __shared__ uint32_t t_bucket[NTASK], t_rib[NTASK], t_slot[NTASK];
    __shared__ uint32_t t_pfx[NTASK], t_rib2[NTASK], t_cslot[NTASK], t_res[NTASK];
    __shared__ uint32_t dbk[NF][6], dpfx[NF][6];
    __shared__ uint32_t ccnt[NTASK];

    const int t = threadIdx.x;
    const int b = blockIdx.x & 255;
    const int half = blockIdx.x >> 8;        // features [half*8, half*8+8)
    const int fgl = t & 1;                   // this thread's feature quad: fgl*4..+3 (local)
    const float INFV = __uint_as_float(0x7F800000u);

    const size_t mstride = (*flag) ? (size_t)1 : (size_t)4;
    const unsigned char* __restrict__ mrow = mb + (size_t)b * S_DIM * mstride;
    const float4* __restrict__ base4 = reinterpret_cast<const float4*>(in)
        + (size_t)b * S_DIM * 4 + (size_t)half * 2 + (size_t)fgl;

    // ---- clear L1 hist ----
    for (int i = t; i < 8192; i += NTH) uni[i] = 0u;
    __syncthreads();

    // ---- pass0 ----
    float sumv[4] = {0.f, 0.f, 0.f, 0.f}, ssqv[4] = {0.f, 0.f, 0.f, 0.f};
    uint32_t kmn[4] = {~0u, ~0u, ~0u, ~0u}, kmx[4] = {0u, 0u, 0u, 0u};
    uint32_t cnt = 0;
    const uint32_t hb = (uint32_t)fgl * 4u * L1BINS;
    #pragma unroll 4
    for (int i = 0; i < NIT; ++i) {
        int s = i * 256 + (t >> 1);
        float4 v = base4[(size_t)s * 4];
        uint32_t m = mrow[(size_t)s * mstride];
        cnt += m;
        float vv[4] = {v.x, v.y, v.z, v.w};
        #pragma unroll
        for (int q = 0; q < 4; ++q) {
            float vh = m ? vv[q] : INFV;
            uint32_t key = enc_key(vh);
            atomicAdd(&uni[hb + (uint32_t)q * L1BINS + (key >> 22)], 1u);
            kmn[q] = umn(kmn[q], key);
            kmx[q] = umx(kmx[q], m ? key : 0u);
            float vs = m ? vv[q] : 0.f;
            sumv[q] += vs;
            ssqv[q] = fmaf(vs, vs, ssqv[q]);
        }
    }

    // ---- block stat reduction (class-preserving shuffles, offsets even) ----
    #pragma unroll
    for (int off = 32; off >= 2; off >>= 1) {
        #pragma unroll
        for (int q = 0; q < 4; ++q) {
            sumv[q] += __shfl_down(sumv[q], off);
            ssqv[q] += __shfl_down(ssqv[q], off);
            kmn[q] = umn(kmn[q], __shfl_down(kmn[q], off));
            kmx[q] = umx(kmx[q], __shfl_down(kmx[q], off));
        }
        cnt += __shfl_down(cnt, off);
    }
    {
        int w = t >> 6, lane = t & 63;
        if (lane < 2) {
            #pragma unroll
            for (int q = 0; q < 4; ++q) {
                p_sum[w][lane * 4 + q] = sumv[q];
                p_ssq[w][lane * 4 + q] = ssqv[q];
                p_kmin[w][lane * 4 + q] = kmn[q];
                p_kmax[w][lane * 4 + q] = kmx[q];
            }
            if (lane == 0) p_cnt[w] = cnt;   // class-0 lanes cover every s once
        }
    }
    __syncthreads();
    if (t < NF) {
        float s0 = 0.f, q0 = 0.f;
        uint32_t mnv = ~0u, mxv = 0u;
        for (int w = 0; w < 8; ++w) {
            s0 += p_sum[w][t]; q0 += p_ssq[w][t];
            mnv = umn(mnv, p_kmin[w][t]); mxv = umx(mxv, p_kmax[w][t]);
        }
        s_sum[t] = s0; s_ssq[t] = q0; s_kmin[t] = mnv; s_kmax[t] = mxv;
        if (t == 0) {
            uint32_t nn = 0;
            for (int w = 0; w < 8; ++w) nn += p_cnt[w];
            s_n = nn;
        }
    }
    __syncthreads();
    const uint32_t n = s_n;

    if (n == 0) {                            // whole batch row masked out
        if (t < NF) {
            int fg = half * NF + t;
            float* pb = pooled + (size_t)b * D_DIM;
            if (fg == 0) pb[0] = 0.f;
            pb[1 + fg] = 0.f; pb[17 + fg] = 0.f; pb[33 + fg] = 0.f;
            pb[49 + fg] = 0.f; pb[65 + fg] = 0.f; pb[81 + fg] = 0.f; pb[97 + fg] = 0.f;
        }
        return;
    }

    // ---- chunk sums + wave-shuffle inclusive scan (wave w = feature w) ----
    {
        int fl = t >> 6, l = t & 63;
        uint32_t csum = 0;
        #pragma unroll
        for (int k2 = 0; k2 < 16; ++k2) csum += uni[fl * L1BINS + l * 16 + k2];
        #pragma unroll
        for (int off = 1; off < 64; off <<= 1) {
            uint32_t o = __shfl_up(csum, off);
            if (l >= off) csum += o;
        }
        chunks[fl][l] = csum;
    }
    __syncthreads();

    // ---- L1 bucket locate (48 rank tasks) ----
    if (t < NTASK) {
        int fl = t / 6, j = t % 6, q = j >> 1;
        float pos = 0.25f * (float)(q + 1) * (float)(n - 1);
        uint32_t r = (j & 1) ? (uint32_t)ceilf(pos) : (uint32_t)floorf(pos);
        int lo2 = 0, hi2 = 63;
        while (lo2 < hi2) {                  // first chunk with incl > r
            int mid = (lo2 + hi2) >> 1;
            if (chunks[fl][mid] > r) hi2 = mid; else lo2 = mid + 1;
        }
        uint32_t acc = lo2 ? chunks[fl][lo2 - 1] : 0u;
        int bin = lo2 * 16;
        while (true) {
            uint32_t h = uni[fl * L1BINS + bin];
            if (acc + h > r) break;
            acc += h; ++bin;
        }
        t_bucket[t] = (uint32_t)bin;
        t_rib[t] = r - acc;
    }
    __syncthreads();
    if (t < NF) {                            // dedupe buckets (nondecreasing in j)
        int d = 0; uint32_t prev = 0xFFFFFFFFu;
        for (int j = 0; j < 6; ++j) {
            uint32_t bk = t_bucket[t * 6 + j];
            if (j == 0 || bk != prev) { dbk[t][d] = bk; ++d; prev = bk; }
            t_slot[t * 6 + j] = (uint32_t)(t * 6 + d - 1);
        }
        for (int j = d; j < 6; ++j) dbk[t][j] = 0xFFFFFFFFu;
    }
    __syncthreads();

    uint32_t dbkr[4][6];
    #pragma unroll
    for (int q = 0; q < 4; ++q)
        #pragma unroll
        for (int j = 0; j < 6; ++j) dbkr[q][j] = dbk[fgl * 4 + q][j];
    // hist no longer needed -> clear L2 region + ccnt
    for (int i = t; i < NTASK * L2BINS; i += NTH) uni[i] = 0u;
    if (t < NTASK) ccnt[t] = 0u;
    __syncthreads();

    // ---- rescan1: fill L2 histograms for deduped buckets ----
    #pragma unroll 2
    for (int i = 0; i < NIT; ++i) {
        int s = i * 256 + (t >> 1);
        float4 v = base4[(size_t)s * 4];
        uint32_t m = mrow[(size_t)s * mstride];
        float vv[4] = {v.x, v.y, v.z, v.w};
        #pragma unroll
        for (int q = 0; q < 4; ++q) {
            float vh = m ? vv[q] : INFV;
            uint32_t key = enc_key(vh);
            uint32_t b10 = key >> 22;
            uint32_t l2 = (key >> 15) & 127u;
            #pragma unroll
            for (int j = 0; j < 6; ++j)
                if (b10 == dbkr[q][j])
                    atomicAdd(&uni[(uint32_t)((fgl * 4 + q) * 6 + j) * L2BINS + l2], 1u);
        }
    }
    __syncthreads();

    // ---- L2 locate ----
    if (t < NTASK) {
        uint32_t slot = t_slot[t];
        uint32_t rib = t_rib[t];
        uint32_t base = slot * L2BINS;
        uint32_t gs[8];
        #pragma unroll
        for (int g = 0; g < 8; ++g) {
            uint32_t sg = 0;
            #pragma unroll
            for (int k2 = 0; k2 < 16; ++k2) sg += uni[base + g * 16 + k2];
            gs[g] = sg;
        }
        uint32_t acc = 0; int g2 = 0;
        while (g2 < 7 && acc + gs[g2] <= rib) { acc += gs[g2]; ++g2; }
        int bin2 = g2 * 16;
        while (true) {
            uint32_t h = uni[base + bin2];
            if (acc + h > rib) break;
            acc += h; ++bin2;
        }
        t_pfx[t] = (t_bucket[t] << 7) | (uint32_t)bin2;
        t_rib2[t] = rib - acc;
    }
    __syncthreads();
    if (t < NF) {                            // dedupe 17-bit prefixes
        int e = 0; uint32_t prev = 0xFFFFFFFFu;
        for (int j = 0; j < 6; ++j) {
            uint32_t p = t_pfx[t * 6 + j];
            if (j == 0 || p != prev) { dpfx[t][e] = p; ++e; prev = p; }
            t_cslot[t * 6 + j] = (uint32_t)(t * 6 + e - 1);
        }
        for (int j = e; j < 6; ++j) dpfx[t][j] = 0xFFFFFFFFu;
    }
    __syncthreads();

    uint32_t dpxr[4][6];
    #pragma unroll
    for (int q = 0; q < 4; ++q)
        #pragma unroll
        for (int j = 0; j < 6; ++j) dpxr[q][j] = dpfx[fgl * 4 + q][j];
    __syncthreads();

    // ---- rescan2: compact candidates per prefix (cand @ uni+6144, no clear needed) ----
    #pragma unroll 2
    for (int i = 0; i < NIT; ++i) {
        int s = i * 256 + (t >> 1);
        float4 v = base4[(size_t)s * 4];
        uint32_t m = mrow[(size_t)s * mstride];
        float vv[4] = {v.x, v.y, v.z, v.w};
        #pragma unroll
        for (int q = 0; q < 4; ++q) {
            float vh = m ? vv[q] : INFV;
            uint32_t key = enc_key(vh);
            uint32_t pfx = key >> 15;
            #pragma unroll
            for (int j = 0; j < 6; ++j)
                if (pfx == dpxr[q][j]) {
                    uint32_t cs = (uint32_t)((fgl * 4 + q) * 6 + j);
                    uint32_t p = atomicAdd(&ccnt[cs], 1u);
                    if (p < CAP) uni[6144 + cs * CAP + p] = key;
                }
        }
    }
    __syncthreads();

    // ---- rank-count over candidates (broadcast LDS reads, 2 tasks/wave) ----
    #pragma unroll
    for (int rnd = 0; rnd < 3; ++rnd) {
        int tk = rnd * 16 + (t >> 5);
        int si = t & 31;
        if (tk < NTASK) {
            uint32_t cs = t_cslot[tk];
            uint32_t c = umn(ccnt[cs], (uint32_t)CAP);
            if ((uint32_t)si < c) {
                uint32_t kk = uni[6144 + cs * CAP + si];
                uint32_t cntl = 0;
                for (uint32_t e2 = 0; e2 < c; ++e2) {
                    uint32_t ke = uni[6144 + cs * CAP + e2];
                    cntl += (ke < kk || (ke == kk && e2 < (uint32_t)si)) ? 1u : 0u;
                }
                uint32_t rib2 = t_rib2[tk];
                if (cntl == rib2) t_res[tk] = kk;
                if ((uint32_t)si == c - 1 && rib2 >= c) t_res[tk] = kk;  // cap-overflow fallback
            }
        }
    }
    __syncthreads();

    // ---- final write ----
    if (t < NF) {
        int fg = half * NF + t;
        float nf = (float)n;
        float mean = s_sum[t] / nf;
        float varn = s_ssq[t] - s_sum[t] * s_sum[t] / nf;
        float denom = (float)(n >= 2 ? n - 1 : 1);
        float stdv = sqrtf(fmaxf(varn, 0.f) / denom);
        float qv[3];
        #pragma unroll
        for (int q = 0; q < 3; ++q) {
            float pos = 0.25f * (float)(q + 1) * (float)(n - 1);
            float frac = pos - floorf(pos);
            float lov = dec_key(t_res[t * 6 + 2 * q]);
            float hiv = dec_key(t_res[t * 6 + 2 * q + 1]);
            qv[q] = lov * (1.f - frac) + hiv * frac;
        }
        float* pb = pooled + (size_t)b * D_DIM;
        if (fg == 0) pb[0] = nf;
        pb[1 + fg] = mean;
        pb[17 + fg] = qv[1];
        pb[33 + fg] = dec_key(s_kmin[t]);
        pb[49 + fg] = dec_key(s_kmax[t]);
        pb[65 + fg] = stdv;
        pb[81 + fg] = qv[0];
        pb[97 + fg] = qv[2];
    }
}

// ---------------------------------------------------------------------------
// MLP: 113 -> 16 -> 4 -> 1, one wave per batch row.
// ---------------------------------------------------------------------------
__global__ __launch_bounds__(64) void mlp_kernel(
        const float* __restrict__ pooled,
        const float* __restrict__ W1, const float* __restrict__ b1,
        const float* __restrict__ W2, const float* __restrict__ b2,
        const float* __restrict__ W3, const float* __restrict__ b3,
        float* __restrict__ out) {
    int b = blockIdx.x;
    int lane = threadIdx.x;
    const float* p = pooled + (size_t)b * D_DIM;
    float h = (lane < 16) ? b1[lane] : 0.f;
    for (int i = 0; i < D_DIM; ++i) {
        float pv = p[i];
        if (lane < 16) h += pv * W1[i * 16 + lane];
    }
    if (lane < 16) h = fmaxf(h, 0.f);
    float h2 = (lane < 4) ? b2[lane] : 0.f;
    for (int j = 0; j < 16; ++j) {
        float hj = __shfl(h, j);
        if (lane < 4) h2 += hj * W2[j * 4 + lane];
    }
    if (lane < 4) h2 = fmaxf(h2, 0.f);
    float o = 0.f;
    for (int j = 0; j < 4; ++j) {
        float hj = __shfl(h2, j);
        o += hj * W3[j];
    }
    if (lane == 0) out[b] = o + b3[0];
}

extern "C" void kernel_launch(void* const* d_in, const int* in_sizes, int n_in,
                              void* d_out, int out_size, void* d_ws, size_t ws_size,
                              hipStream_t stream) {
    const float* inputs = (const float*)d_in[0];
    const unsigned char* mask = (const unsigned char*)d_in[1];
    const float* W1 = (const float*)d_in[2];
    const float* b1 = (const float*)d_in[3];
    const float* W2 = (const float*)d_in[4];
    const float* b2 = (const float*)d_in[5];
    const float* W3 = (const float*)d_in[6];
    const float* b3 = (const float*)d_in[7];
    float* out = (float*)d_out;

    float* pooled = (float*)d_ws;                                  // 256*113*4 B
    unsigned int* flag = (unsigned int*)((char*)d_ws + 115712);

    detect_mask_kernel<<<1, 256, 0, stream>>>(mask, flag);
    stats_kernel<<<2 * B_DIM, NTH, 0, stream>>>(inputs, mask, flag, pooled);
    mlp_kernel<<<B_DIM, 64, 0, stream>>>(pooled, W1, b1, W2, b2, W3, b3, out);
}

// Round 3
// 221.412 us; speedup vs baseline: 2.0389x; 1.2780x over previous
//
#include <hip/hip_runtime.h>
#include <stdint.h>

#define B_DIM 256
#define S_DIM 16384
#define D_DIM 113          // 7*16+1

#define NTH 1024
#define NF 8               // features per block (2 blocks per batch row)
#define NIT 32             // float4 iterations per thread (S / (NTH/2))
#define L1BINS 4096        // 12-bit level-1 histogram per feature (packed u16)
#define CANDCAP 1472       // candidate cap per feature (expected ~330-700)
#define MHSIZE 384         // 6 dedup slots * 64 sub-bins
#define TCAP 16            // tiny-compact cap per task (expected ~2.6)
#define NTASK 48           // NF * 6 rank tasks
#define MH_OFF 11776       // dword offsets inside uni[16384]
#define TC_OFF 14848
#define KEYINF 0xFF800000u

__device__ __forceinline__ uint32_t enc_key(float v) {
    uint32_t u = __float_as_uint(v);
    uint32_t m = (uint32_t)((int32_t)u >> 31) | 0x80000000u;
    return u ^ m;
}
__device__ __forceinline__ float dec_key(uint32_t k) {
    uint32_t u = (k & 0x80000000u) ? (k ^ 0x80000000u) : ~k;
    return __uint_as_float(u);
}
__device__ __forceinline__ uint32_t umn(uint32_t a, uint32_t b) { return a < b ? a : b; }
__device__ __forceinline__ uint32_t umx(uint32_t a, uint32_t b) { return a > b ? a : b; }

// ---------------------------------------------------------------------------
// Detect mask element width: bool(1B) vs int32(4B). For int32 0/1 values every
// byte at (idx & 3) != 0 is zero; random bool bytes are not all zero.
// flag = 1 -> 1-byte elements, flag = 0 -> 4-byte elements.
// ---------------------------------------------------------------------------
__global__ void detect_mask_kernel(const unsigned char* __restrict__ mb,
                                   unsigned int* __restrict__ flag) {
    __shared__ unsigned int acc[256];
    int t = threadIdx.x;
    unsigned int x = 0;
    for (int i = 0; i < 256; ++i) {
        int idx = t * 256 + i;
        if ((idx & 3) != 0) x |= mb[idx];
    }
    acc[t] = x;
    __syncthreads();
    for (int off = 128; off; off >>= 1) {
        if (t < off) acc[t] |= acc[t + off];
        __syncthreads();
    }
    if (t == 0) *flag = (acc[0] != 0) ? 1u : 0u;
}

// ---------------------------------------------------------------------------
// Pack mask to a bitmap: bits[e>>5] bit (e&31). One byte load per element,
// wave ballot produces 64 bits; lanes 0/32 write the two dwords.
// ---------------------------------------------------------------------------
__global__ __launch_bounds__(256) void mask_bits_kernel(
        const unsigned char* __restrict__ mb, const unsigned int* __restrict__ flag,
        uint32_t* __restrict__ bits) {
    size_t stride = (*flag) ? (size_t)1 : (size_t)4;
    size_t e = (size_t)blockIdx.x * 256 + threadIdx.x;
    uint32_t m = mb[e * stride] ? 1u : 0u;
    unsigned long long bal = __ballot(m);
    int lane = threadIdx.x & 63;
    if (lane == 0) bits[e >> 5] = (uint32_t)bal;
    else if (lane == 32) bits[e >> 5] = (uint32_t)(bal >> 32);
}

// ---------------------------------------------------------------------------
// Fused stats kernel, 2 global passes. Block = (b, half of 8 features),
// 1024 threads (16 waves), 2 blocks/CU (~71KB LDS).
//  pass0: stats + 12-bit L1 hist (packed u16, 2 bins/dword; n<=16384 so no carry)
//  locate L1 buckets for 6 ranks/feature, dedupe, compute rank-within-union
//  pass1: compact keys of deduped buckets into LDS (cap 1472/feature) + 6-bit
//         sub-histogram per dedup slot
//  then LDS-only: prefix scan, binary-search locate, 18-bit-prefix compact
//  (cap 16), exact rank-count. Masked elements -> +inf key (bin 4088, above
//  every finite bin) so they can never pollute buckets.
// ---------------------------------------------------------------------------
template<bool MBITS>
__global__ __launch_bounds__(NTH, 8) void stats_kernel(
        const float* __restrict__ in, const uint32_t* __restrict__ mbits,
        const unsigned char* __restrict__ mb, const unsigned int* __restrict__ flag,
        float* __restrict__ pooled) {
    __shared__ uint32_t uni[16384];          // 64KB: hist -> cand|mh|tc
    __shared__ uint32_t chunks[NF][64];
    __shared__ float p_sum[16][NF], p_ssq[16][NF];
    __shared__ uint32_t p_kmin[16][NF], p_kmax[16][NF];
    __shared__ float s_sum[NF], s_ssq[NF];
    __shared__ uint32_t s_kmin[NF], s_kmax[NF];
    __shared__ uint32_t s_n;
    __shared__ uint32_t t_bucket[NTASK], t_rib[NTASK], t_urank[NTASK];
    __shared__ uint32_t t3bin[NTASK], t_rib3[NTASK], t_res[NTASK];
    __shared__ uint32_t dbk[NF][6];
    __shared__ uint32_t ccnt[NF], tcc[NTASK];

    const int t = threadIdx.x;
    const int b = blockIdx.x & 255;
    const int half = blockIdx.x >> 8;
    const int fgl = t & 1;                   // feature quad (0: f0-3, 1: f4-7)
    const float INFV = __uint_as_float(0x7F800000u);

    const float4* __restrict__ base4 = reinterpret_cast<const float4*>(in)
        + (size_t)b * S_DIM * 4 + (size_t)half * 2 + (size_t)fgl;

    const uint32_t* mrowbits = nullptr;
    size_t mstride = 1;
    const unsigned char* mrow = nullptr;
    if (MBITS) {
        mrowbits = mbits + (size_t)b * 512;
    } else {
        mstride = (*flag) ? (size_t)1 : (size_t)4;
        mrow = mb + (size_t)b * S_DIM * mstride;
    }

    // ---- clear hist; count n ----
    for (int i = t; i < 16384; i += NTH) uni[i] = 0u;
    if (t == 0) s_n = 0u;
    __syncthreads();
    {
        uint32_t c = 0;
        if (MBITS) {
            if (t < 512) c = __popc(mrowbits[t]);
        } else {
            #pragma unroll
            for (int k2 = 0; k2 < 16; ++k2)
                c += (mrow[(size_t)(t * 16 + k2) * mstride] != 0) ? 1u : 0u;
        }
        #pragma unroll
        for (int off = 32; off; off >>= 1) c += __shfl_down(c, off);
        if ((t & 63) == 0 && c) atomicAdd(&s_n, c);
    }
    __syncthreads();
    const uint32_t n = s_n;

    if (n == 0) {                            // whole batch row masked out
        if (t < NF) {
            int fg = half * NF + t;
            float* pb = pooled + (size_t)b * D_DIM;
            if (fg == 0) pb[0] = 0.f;
            pb[1 + fg] = 0.f; pb[17 + fg] = 0.f; pb[33 + fg] = 0.f;
            pb[49 + fg] = 0.f; pb[65 + fg] = 0.f; pb[81 + fg] = 0.f; pb[97 + fg] = 0.f;
        }
        return;
    }

    // ---- pass0: stats + L1 hist ----
    float sumv[4] = {0.f, 0.f, 0.f, 0.f}, ssqv[4] = {0.f, 0.f, 0.f, 0.f};
    uint32_t kmn[4] = {~0u, ~0u, ~0u, ~0u}, kmx[4] = {0u, 0u, 0u, 0u};
    #pragma unroll 4
    for (int i = 0; i < NIT; ++i) {
        int s = i * 512 + (t >> 1);
        float4 v = base4[(size_t)s * 4];
        uint32_t m;
        if (MBITS) {
            uint32_t mw = mrowbits[i * 16 + (t >> 6)];
            m = (mw >> ((t >> 1) & 31)) & 1u;
        } else {
            m = mrow[(size_t)s * mstride] ? 1u : 0u;
        }
        float vv[4] = {v.x, v.y, v.z, v.w};
        #pragma unroll
        for (int q = 0; q < 4; ++q) {
            float vh = m ? vv[q] : INFV;
            uint32_t key = enc_key(vh);
            kmn[q] = umn(kmn[q], key);
            kmx[q] = umx(kmx[q], m ? key : 0u);
            float vs = m ? vv[q] : 0.f;
            sumv[q] += vs;
            ssqv[q] = fmaf(vs, vs, ssqv[q]);
            if (m) {
                uint32_t bin = key >> 20;
                atomicAdd(&uni[((fgl * 4 + q) << 11) + (bin >> 1)],
                          (bin & 1) ? 65536u : 1u);
            }
        }
    }

    // ---- block stat reduction (parity-preserving shuffles) ----
    #pragma unroll
    for (int off = 32; off >= 2; off >>= 1) {
        #pragma unroll
        for (int q = 0; q < 4; ++q) {
            sumv[q] += __shfl_down(sumv[q], off);
            ssqv[q] += __shfl_down(ssqv[q], off);
            kmn[q] = umn(kmn[q], __shfl_down(kmn[q], off));
            kmx[q] = umx(kmx[q], __shfl_down(kmx[q], off));
        }
    }
    {
        int w = t >> 6, lane = t & 63;
        if (lane < 2) {
            #pragma unroll
            for (int q = 0; q < 4; ++q) {
                p_sum[w][lane * 4 + q] = sumv[q];
                p_ssq[w][lane * 4 + q] = ssqv[q];
                p_kmin[w][lane * 4 + q] = kmn[q];
                p_kmax[w][lane * 4 + q] = kmx[q];
            }
        }
    }
    __syncthreads();
    if (t < NF) {
        float s0 = 0.f, q0 = 0.f;
        uint32_t mnv = ~0u, mxv = 0u;
        for (int w = 0; w < 16; ++w) {
            s0 += p_sum[w][t]; q0 += p_ssq[w][t];
            mnv = umn(mnv, p_kmin[w][t]); mxv = umx(mxv, p_kmax[w][t]);
        }
        s_sum[t] = s0; s_ssq[t] = q0; s_kmin[t] = mnv; s_kmax[t] = mxv;
    }

    // ---- chunk sums (64 bins each, rotated conflict-free) + wave scan ----
    if (t < 512) {
        int f = t >> 6, l = t & 63;
        uint32_t csum = 0;
        int base = (f << 11) + l * 32;
        #pragma unroll
        for (int k2 = 0; k2 < 32; ++k2) {
            uint32_t w = uni[base + ((k2 + l) & 31)];
            csum += (w & 0xFFFFu) + (w >> 16);
        }
        #pragma unroll
        for (int off = 1; off < 64; off <<= 1) {
            uint32_t o = __shfl_up(csum, off);
            if (l >= off) csum += o;
        }
        chunks[f][l] = csum;
    }
    __syncthreads();

    // ---- L1 locate (48 rank tasks) ----
    if (t < NTASK) {
        int f = t / 6, j = t % 6, q = j >> 1;
        float pos = 0.25f * (float)(q + 1) * (float)(n - 1);
        uint32_t r = (j & 1) ? (uint32_t)ceilf(pos) : (uint32_t)floorf(pos);
        int lo = 0, hi = 63;
        while (lo < hi) {                    // first chunk with incl > r
            int mid = (lo + hi) >> 1;
            if (chunks[f][mid] > r) hi = mid; else lo = mid + 1;
        }
        uint32_t acc = lo ? chunks[f][lo - 1] : 0u;
        int bin = lo * 64;
        while (true) {
            uint32_t w = uni[(f << 11) + (bin >> 1)];
            uint32_t h = (w >> ((bin & 1) * 16)) & 0xFFFFu;
            if (acc + h > r) break;
            acc += h; ++bin;
        }
        t_bucket[t] = (uint32_t)bin;
        t_rib[t] = r - acc;
    }
    __syncthreads();

    // ---- dedupe buckets + rank-within-union (reads hist counts) ----
    if (t < NF) {
        uint32_t prev = 0xFFFFFFFFu, cumb = 0, prevcnt = 0;
        int nd = 0;
        #pragma unroll
        for (int j = 0; j < 6; ++j) {
            uint32_t bk = t_bucket[t * 6 + j];
            if (nd == 0 || bk != prev) {
                cumb += prevcnt;
                uint32_t w = uni[(t << 11) + (bk >> 1)];
                prevcnt = (w >> ((bk & 1) * 16)) & 0xFFFFu;
                dbk[t][nd] = bk; ++nd; prev = bk;
            }
            t_urank[t * 6 + j] = t_rib[t * 6 + j] + cumb;
        }
        for (int j = nd; j < 6; ++j) dbk[t][j] = 0xFFFFFFFFu;
        ccnt[t] = 0u;
    }
    if (t < NTASK) tcc[t] = 0u;
    __syncthreads();

    // ---- load dedup set to regs; clear mh region (hist dead now) ----
    uint32_t dbkr[4][6];
    #pragma unroll
    for (int q = 0; q < 4; ++q)
        #pragma unroll
        for (int j = 0; j < 6; ++j) dbkr[q][j] = dbk[fgl * 4 + q][j];
    for (int i = MH_OFF + t; i < TC_OFF; i += NTH) uni[i] = 0u;
    __syncthreads();

    // ---- pass1: compact candidates + 6-bit sub-hist per dedup slot ----
    #pragma unroll 2
    for (int i = 0; i < NIT; ++i) {
        int s = i * 512 + (t >> 1);
        float4 v = base4[(size_t)s * 4];
        uint32_t m;
        if (MBITS) {
            uint32_t mw = mrowbits[i * 16 + (t >> 6)];
            m = (mw >> ((t >> 1) & 31)) & 1u;
        } else {
            m = mrow[(size_t)s * mstride] ? 1u : 0u;
        }
        float vv[4] = {v.x, v.y, v.z, v.w};
        #pragma unroll
        for (int q = 0; q < 4; ++q) {
            float vh = m ? vv[q] : INFV;
            uint32_t key = enc_key(vh);
            uint32_t bin = key >> 20;
            #pragma unroll
            for (int j = 0; j < 6; ++j) {
                if (bin == dbkr[q][j]) {
                    int fq = fgl * 4 + q;
                    uint32_t p = atomicAdd(&ccnt[fq], 1u);
                    if (p < CANDCAP) uni[fq * CANDCAP + p] = key;
                    atomicAdd(&uni[MH_OFF + fq * MHSIZE + j * 64 + ((key >> 14) & 63u)], 1u);
                }
            }
        }
    }
    __syncthreads();

    // ---- mh in-place inclusive scan (wave f, 6 entries/lane) ----
    if (t < 512) {
        int f = t >> 6, l = t & 63;
        int base = MH_OFF + f * MHSIZE + l * 6;
        uint32_t a0, a1, a2, a3, a4, a5, run = 0;
        run += uni[base + 0]; a0 = run;
        run += uni[base + 1]; a1 = run;
        run += uni[base + 2]; a2 = run;
        run += uni[base + 3]; a3 = run;
        run += uni[base + 4]; a4 = run;
        run += uni[base + 5]; a5 = run;
        uint32_t tot = run;
        #pragma unroll
        for (int off = 1; off < 64; off <<= 1) {
            uint32_t o = __shfl_up(tot, off);
            if (l >= off) tot += o;
        }
        uint32_t excl = tot - run;
        uni[base + 0] = a0 + excl; uni[base + 1] = a1 + excl;
        uni[base + 2] = a2 + excl; uni[base + 3] = a3 + excl;
        uni[base + 4] = a4 + excl; uni[base + 5] = a5 + excl;
    }
    __syncthreads();

    // ---- locate3: binary search mh inclusive scan ----
    if (t < NTASK) {
        int f = t / 6;
        uint32_t u = t_urank[t];
        int mb0 = MH_OFF + f * MHSIZE;
        int lo = 0, hi = MHSIZE - 1;
        while (lo < hi) {
            int mid = (lo + hi) >> 1;
            if (uni[mb0 + mid] > u) hi = mid; else lo = mid + 1;
        }
        t3bin[t] = (uint32_t)lo;
        t_rib3[t] = u - (lo ? uni[mb0 + lo - 1] : 0u);
    }
    __syncthreads();

    // ---- tiny compact: candidates matching a task's 18-bit prefix ----
    {
        int f = t >> 7, i0 = t & 127;
        uint32_t c = umn(ccnt[f], (uint32_t)CANDCAP);
        uint32_t db[6], tb[6];
        #pragma unroll
        for (int j = 0; j < 6; ++j) { db[j] = dbk[f][j]; tb[j] = t3bin[f * 6 + j]; }
        for (uint32_t idx = (uint32_t)i0; idx < c; idx += 128) {
            uint32_t key = uni[f * CANDCAP + idx];
            uint32_t bin = key >> 20, sub = (key >> 14) & 63u;
            #pragma unroll
            for (int j = 0; j < 6; ++j) {
                if (bin == db[j]) {
                    uint32_t mb2 = (uint32_t)j * 64u + sub;
                    #pragma unroll
                    for (int jj = 0; jj < 6; ++jj) {
                        if (mb2 == tb[jj]) {
                            uint32_t p = atomicAdd(&tcc[f * 6 + jj], 1u);
                            if (p < TCAP) uni[TC_OFF + (f * 6 + jj) * TCAP + p] = key;
                        }
                    }
                }
            }
        }
    }
    __syncthreads();

    // ---- final exact rank-count (16 lanes per task) ----
    if (t < NTASK * TCAP) {
        int task = t >> 4, si = t & 15;
        uint32_t c = umn(tcc[task], (uint32_t)TCAP);
        if ((uint32_t)si < c) {
            uint32_t kk = uni[TC_OFF + task * TCAP + si];
            uint32_t cl = 0;
            for (uint32_t e = 0; e < c; ++e) {
                uint32_t ke = uni[TC_OFF + task * TCAP + e];
                cl += (ke < kk || (ke == kk && (int)e < si)) ? 1u : 0u;
            }
            uint32_t r3 = t_rib3[task];
            if (cl == r3) t_res[task] = kk;
            if ((uint32_t)si == c - 1 && r3 >= c) t_res[task] = kk;  // overflow fallback
        }
    }
    __syncthreads();

    // ---- final write ----
    if (t < NF) {
        int fg = half * NF + t;
        float nf = (float)n;
        float mean = s_sum[t] / nf;
        float varn = s_ssq[t] - s_sum[t] * s_sum[t] / nf;
        float denom = (float)(n >= 2 ? n - 1 : 1);
        float stdv = sqrtf(fmaxf(varn, 0.f) / denom);
        float qv[3];
        #pragma unroll
        for (int q = 0; q < 3; ++q) {
            float pos = 0.25f * (float)(q + 1) * (float)(n - 1);
            float frac = pos - floorf(pos);
            float lov = dec_key(t_res[t * 6 + 2 * q]);
            float hiv = dec_key(t_res[t * 6 + 2 * q + 1]);
            qv[q] = lov * (1.f - frac) + hiv * frac;
        }
        float* pb = pooled + (size_t)b * D_DIM;
        if (fg == 0) pb[0] = nf;
        pb[1 + fg] = mean;
        pb[17 + fg] = qv[1];
        pb[33 + fg] = dec_key(s_kmin[t]);
        pb[49 + fg] = dec_key(s_kmax[t]);
        pb[65 + fg] = stdv;
        pb[81 + fg] = qv[0];
        pb[97 + fg] = qv[2];
    }
}

// ---------------------------------------------------------------------------
// MLP: 113 -> 16 -> 4 -> 1, one wave per batch row.
// ---------------------------------------------------------------------------
__global__ __launch_bounds__(64) void mlp_kernel(
        const float* __restrict__ pooled,
        const float* __restrict__ W1, const float* __restrict__ b1,
        const float* __restrict__ W2, const float* __restrict__ b2,
        const float* __restrict__ W3, const float* __restrict__ b3,
        float* __restrict__ out) {
    int b = blockIdx.x;
    int lane = threadIdx.x;
    const float* p = pooled + (size_t)b * D_DIM;
    float h = (lane < 16) ? b1[lane] : 0.f;
    for (int i = 0; i < D_DIM; ++i) {
        float pv = p[i];
        if (lane < 16) h += pv * W1[i * 16 + lane];
    }
    if (lane < 16) h = fmaxf(h, 0.f);
    float h2 = (lane < 4) ? b2[lane] : 0.f;
    for (int j = 0; j < 16; ++j) {
        float hj = __shfl(h, j);
        if (lane < 4) h2 += hj * W2[j * 4 + lane];
    }
    if (lane < 4) h2 = fmaxf(h2, 0.f);
    float o = 0.f;
    for (int j = 0; j < 4; ++j) {
        float hj = __shfl(h2, j);
        o += hj * W3[j];
    }
    if (lane == 0) out[b] = o + b3[0];
}

extern "C" void kernel_launch(void* const* d_in, const int* in_sizes, int n_in,
                              void* d_out, int out_size, void* d_ws, size_t ws_size,
                              hipStream_t stream) {
    const float* inputs = (const float*)d_in[0];
    const unsigned char* mask = (const unsigned char*)d_in[1];
    const float* W1 = (const float*)d_in[2];
    const float* b1 = (const float*)d_in[3];
    const float* W2 = (const float*)d_in[4];
    const float* b2 = (const float*)d_in[5];
    const float* W3 = (const float*)d_in[6];
    const float* b3 = (const float*)d_in[7];
    float* out = (float*)d_out;

    float* pooled = (float*)d_ws;                                  // 256*113*4 B
    unsigned int* flag = (unsigned int*)((char*)d_ws + 115712);
    uint32_t* bits = (uint32_t*)((char*)d_ws + 131072);            // 512 KB bitmap
    bool usebits = ws_size >= 655360;

    detect_mask_kernel<<<1, 256, 0, stream>>>(mask, flag);
    if (usebits) {
        mask_bits_kernel<<<(B_DIM * S_DIM) / 256, 256, 0, stream>>>(mask, flag, bits);
        stats_kernel<true><<<2 * B_DIM, NTH, 0, stream>>>(inputs, bits, nullptr, flag, pooled);
    } else {
        stats_kernel<false><<<2 * B_DIM, NTH, 0, stream>>>(inputs, nullptr, mask, flag, pooled);
    }
    mlp_kernel<<<B_DIM, 64, 0, stream>>>(pooled, W1, b1, W2, b2, W3, b3, out);
}

// Round 4
// 161.673 us; speedup vs baseline: 2.7923x; 1.3695x over previous
//
#include <hip/hip_runtime.h>
#include <stdint.h>

#define B_DIM 256
#define S_DIM 16384
#define NTH 1024
#define NIT 64             // S / 256 rows-per-iteration
#define CANDCAP 1536       // candidates per feature (expected max ~350)
#define NTASK 96           // 16 features * 6 rank tasks
#define TCAP 16            // tiny-compact cap per task (expected ~5)
#define MH_OFF 24576       // dword offset of sub-hist region in uni
#define TC_OFF 30720       // dword offset of tiny-compact region in uni
#define KEYINF 0xFF800000u

__device__ __forceinline__ uint32_t enc_key(float v) {
    uint32_t u = __float_as_uint(v);
    uint32_t m = (uint32_t)((int32_t)u >> 31) | 0x80000000u;
    return u ^ m;
}
__device__ __forceinline__ float dec_key(uint32_t k) {
    uint32_t u = (k & 0x80000000u) ? (k ^ 0x80000000u) : ~k;
    return __uint_as_float(u);
}
__device__ __forceinline__ uint32_t umn(uint32_t a, uint32_t b) { return a < b ? a : b; }
__device__ __forceinline__ uint32_t umx(uint32_t a, uint32_t b) { return a > b ? a : b; }

// ---------------------------------------------------------------------------
// One block per batch row b, 1024 threads, all 16 features.
// Fully-coalesced reads: thread t covers feature-quad (t&3) of row i*256+(t>>2)
// -> each wave reads 1024 contiguous bytes (16 full 64B lines, zero waste).
//
//  phase A: clear hist, detect mask dtype (bool-1B vs int32-4B) on a 16KB
//           window of this block: int32 0/1 data has all non-LSB bytes zero.
//  phase B: stage mask bitmap to LDS via ballot; popcount -> n.
//  pass0:   stats (sum/ssq/min/max) + 12-bit L1 histogram (packed u16).
//  locate:  per-feature chunk scan + binary search + bin walk for 6 ranks,
//           dedupe buckets, rank-within-union.
//  pass1:   re-read, compact keys of deduped buckets to LDS (cap 1536/feat)
//           + 6-bit sub-histogram per dedup slot.
//  LDS-only: sub-hist scan, locate, 18-bit-prefix tiny compact (cap 16),
//           exact rank-count.
//  epilogue: build pooled[113] in LDS, run the 113->16->4->1 MLP on wave 0,
//           write out[b]. (Empty row -> pooled = zeros -> MLP(0).)
// ---------------------------------------------------------------------------
__global__ __launch_bounds__(NTH, 4) void fused_kernel(
        const float* __restrict__ in, const unsigned char* __restrict__ mb,
        const float* __restrict__ W1, const float* __restrict__ b1,
        const float* __restrict__ W2, const float* __restrict__ b2,
        const float* __restrict__ W3, const float* __restrict__ b3,
        float* __restrict__ out) {
    __shared__ uint32_t uni[32768];          // 128KB: hist[16][2048] -> cand|mh|tc
    __shared__ uint32_t chunks[16][64];
    __shared__ float p_sum[16][16], p_ssq[16][16];
    __shared__ uint32_t p_kmin[16][16], p_kmax[16][16];
    __shared__ float s_sum[16], s_ssq[16];
    __shared__ uint32_t s_kmin[16], s_kmax[16];
    __shared__ uint32_t s_n, s_det;
    __shared__ uint32_t t_bucket[NTASK], t_rib[NTASK], t_urank[NTASK];
    __shared__ uint32_t t3bin[NTASK], t_rib3[NTASK], t_res[NTASK];
    __shared__ uint32_t dbk[16][6];
    __shared__ uint32_t ccnt[16], tcc[NTASK];
    __shared__ uint32_t bitsL[512];
    __shared__ float pool[128];

    const int t = threadIdx.x;
    const int b = blockIdx.x;
    const int q4 = t & 3;                    // feature quad: features q4*4..q4*4+3
    const float INFV = __uint_as_float(0x7F800000u);

    // ---- phase A: clear hist + detect mask dtype ----
    #pragma unroll
    for (int i = 0; i < 32; ++i) uni[i * NTH + t] = 0u;
    if (t == 0) { s_n = 0u; s_det = 0u; }
    {
        const uint32_t* mw32 = reinterpret_cast<const uint32_t*>(mb);
        uint32_t x = 0;
        #pragma unroll
        for (int i = 0; i < 4; ++i)
            x |= mw32[b * 4096 + i * NTH + t] & 0xFFFFFF00u;   // 16KB window, in-bounds for bool & int32
        unsigned long long any = __ballot(x != 0);
        if ((t & 63) == 0 && any) atomicOr(&s_det, 1u);
    }
    __syncthreads();
    const size_t mstride = s_det ? (size_t)1 : (size_t)4;
    const unsigned char* __restrict__ mrow = mb + (size_t)b * S_DIM * mstride;

    // ---- phase B: stage mask bitmap ----
    #pragma unroll
    for (int it = 0; it < 16; ++it) {
        int e = it * 1024 + t;
        uint32_t m = mrow[(size_t)e * mstride] ? 1u : 0u;
        unsigned long long bal = __ballot(m);
        int lane = t & 63;
        if (lane == 0) bitsL[e >> 5] = (uint32_t)bal;
        else if (lane == 32) bitsL[e >> 5] = (uint32_t)(bal >> 32);
    }
    __syncthreads();
    if (t < 512) {
        uint32_t c = __popc(bitsL[t]);
        #pragma unroll
        for (int off = 32; off; off >>= 1) c += __shfl_down(c, off);
        if ((t & 63) == 0 && c) atomicAdd(&s_n, c);
    }
    __syncthreads();
    const uint32_t n = s_n;

    const float4* __restrict__ base4 = reinterpret_cast<const float4*>(in)
        + (size_t)b * S_DIM * 4 + q4;

    if (n != 0) {
        // ---- pass0: stats + L1 hist ----
        float sumv[4] = {0.f, 0.f, 0.f, 0.f}, ssqv[4] = {0.f, 0.f, 0.f, 0.f};
        uint32_t kmn[4] = {~0u, ~0u, ~0u, ~0u}, kmx[4] = {0u, 0u, 0u, 0u};
        #pragma unroll 4
        for (int i = 0; i < NIT; ++i) {
            int s = i * 256 + (t >> 2);
            float4 v = base4[(size_t)s * 4];
            uint32_t mw = bitsL[i * 8 + (t >> 7)];
            uint32_t m = (mw >> ((t >> 2) & 31)) & 1u;
            float vv[4] = {v.x, v.y, v.z, v.w};
            #pragma unroll
            for (int q = 0; q < 4; ++q) {
                float vh = m ? vv[q] : INFV;
                uint32_t key = enc_key(vh);
                kmn[q] = umn(kmn[q], key);
                kmx[q] = umx(kmx[q], m ? key : 0u);
                float vs = m ? vv[q] : 0.f;
                sumv[q] += vs;
                ssqv[q] = fmaf(vs, vs, ssqv[q]);
                if (m) {
                    uint32_t bin = key >> 20;
                    atomicAdd(&uni[(((uint32_t)q4 * 4 + q) << 11) + (bin >> 1)],
                              (bin & 1) ? 65536u : 1u);
                }
            }
        }

        // ---- block stat reduction (quad-class-preserving shuffles) ----
        #pragma unroll
        for (int off = 32; off >= 4; off >>= 1) {
            #pragma unroll
            for (int q = 0; q < 4; ++q) {
                sumv[q] += __shfl_down(sumv[q], off);
                ssqv[q] += __shfl_down(ssqv[q], off);
                kmn[q] = umn(kmn[q], __shfl_down(kmn[q], off));
                kmx[q] = umx(kmx[q], __shfl_down(kmx[q], off));
            }
        }
        {
            int w = t >> 6, lane = t & 63;
            if (lane < 4) {
                #pragma unroll
                for (int q = 0; q < 4; ++q) {
                    p_sum[w][lane * 4 + q] = sumv[q];
                    p_ssq[w][lane * 4 + q] = ssqv[q];
                    p_kmin[w][lane * 4 + q] = kmn[q];
                    p_kmax[w][lane * 4 + q] = kmx[q];
                }
            }
        }
        __syncthreads();
        if (t < 16) {
            float s0 = 0.f, q0 = 0.f;
            uint32_t mnv = ~0u, mxv = 0u;
            for (int w = 0; w < 16; ++w) {
                s0 += p_sum[w][t]; q0 += p_ssq[w][t];
                mnv = umn(mnv, p_kmin[w][t]); mxv = umx(mxv, p_kmax[w][t]);
            }
            s_sum[t] = s0; s_ssq[t] = q0; s_kmin[t] = mnv; s_kmax[t] = mxv;
        }

        // ---- chunk sums (rotated, conflict-free) + wave scan; wave w = feature w ----
        {
            int f = t >> 6, l = t & 63;
            uint32_t csum = 0;
            int base = (f << 11) + l * 32;
            #pragma unroll
            for (int k2 = 0; k2 < 32; ++k2) {
                uint32_t w = uni[base + ((k2 + l) & 31)];
                csum += (w & 0xFFFFu) + (w >> 16);
            }
            #pragma unroll
            for (int off = 1; off < 64; off <<= 1) {
                uint32_t o = __shfl_up(csum, off);
                if (l >= off) csum += o;
            }
            chunks[f][l] = csum;
        }
        __syncthreads();

        // ---- L1 locate (96 rank tasks) ----
        if (t < NTASK) {
            int f = t / 6, j = t % 6, q = j >> 1;
            float pos = 0.25f * (float)(q + 1) * (float)(n - 1);
            uint32_t r = (j & 1) ? (uint32_t)ceilf(pos) : (uint32_t)floorf(pos);
            int lo = 0, hi = 63;
            while (lo < hi) {
                int mid = (lo + hi) >> 1;
                if (chunks[f][mid] > r) hi = mid; else lo = mid + 1;
            }
            uint32_t acc = lo ? chunks[f][lo - 1] : 0u;
            int bin = lo * 64;
            while (true) {
                uint32_t w = uni[(f << 11) + (bin >> 1)];
                uint32_t h = (w >> ((bin & 1) * 16)) & 0xFFFFu;
                if (acc + h > r) break;
                acc += h; ++bin;
            }
            t_bucket[t] = (uint32_t)bin;
            t_rib[t] = r - acc;
        }
        __syncthreads();

        // ---- dedupe buckets + rank-within-union ----
        if (t < 16) {
            uint32_t prev = 0xFFFFFFFFu, cumb = 0, prevcnt = 0;
            int nd = 0;
            #pragma unroll
            for (int j = 0; j < 6; ++j) {
                uint32_t bk = t_bucket[t * 6 + j];
                if (nd == 0 || bk != prev) {
                    cumb += prevcnt;
                    uint32_t w = uni[(t << 11) + (bk >> 1)];
                    prevcnt = (w >> ((bk & 1) * 16)) & 0xFFFFu;
                    dbk[t][nd] = bk; ++nd; prev = bk;
                }
                t_urank[t * 6 + j] = t_rib[t * 6 + j] + cumb;
            }
            for (int j = nd; j < 6; ++j) dbk[t][j] = 0xFFFFFFFFu;
            ccnt[t] = 0u;
        }
        if (t < NTASK) tcc[t] = 0u;
        __syncthreads();

        uint32_t dbkr[4][6];
        #pragma unroll
        for (int q = 0; q < 4; ++q)
            #pragma unroll
            for (int j = 0; j < 6; ++j) dbkr[q][j] = dbk[q4 * 4 + q][j];
        for (int i = MH_OFF + t; i < TC_OFF; i += NTH) uni[i] = 0u;
        __syncthreads();

        // ---- pass1: compact candidates + 6-bit sub-hist ----
        #pragma unroll 2
        for (int i = 0; i < NIT; ++i) {
            int s = i * 256 + (t >> 2);
            float4 v = base4[(size_t)s * 4];
            uint32_t mw = bitsL[i * 8 + (t >> 7)];
            uint32_t m = (mw >> ((t >> 2) & 31)) & 1u;
            float vv[4] = {v.x, v.y, v.z, v.w};
            #pragma unroll
            for (int q = 0; q < 4; ++q) {
                float vh = m ? vv[q] : INFV;
                uint32_t key = enc_key(vh);
                uint32_t bin = key >> 20;
                #pragma unroll
                for (int j = 0; j < 6; ++j) {
                    if (bin == dbkr[q][j]) {
                        int fq = q4 * 4 + q;
                        uint32_t p = atomicAdd(&ccnt[fq], 1u);
                        if (p < CANDCAP) uni[fq * CANDCAP + p] = key;
                        atomicAdd(&uni[MH_OFF + fq * 384 + j * 64 + ((key >> 14) & 63u)], 1u);
                    }
                }
            }
        }
        __syncthreads();

        // ---- sub-hist in-place inclusive scan (wave f, 6 entries/lane) ----
        {
            int f = t >> 6, l = t & 63;
            int base = MH_OFF + f * 384 + l * 6;
            uint32_t a0, a1, a2, a3, a4, a5, run = 0;
            run += uni[base + 0]; a0 = run;
            run += uni[base + 1]; a1 = run;
            run += uni[base + 2]; a2 = run;
            run += uni[base + 3]; a3 = run;
            run += uni[base + 4]; a4 = run;
            run += uni[base + 5]; a5 = run;
            uint32_t tot = run;
            #pragma unroll
            for (int off = 1; off < 64; off <<= 1) {
                uint32_t o = __shfl_up(tot, off);
                if (l >= off) tot += o;
            }
            uint32_t excl = tot - run;
            uni[base + 0] = a0 + excl; uni[base + 1] = a1 + excl;
            uni[base + 2] = a2 + excl; uni[base + 3] = a3 + excl;
            uni[base + 4] = a4 + excl; uni[base + 5] = a5 + excl;
        }
        __syncthreads();

        // ---- locate in sub-hist scan ----
        if (t < NTASK) {
            int f = t / 6;
            uint32_t u = t_urank[t];
            int mb0 = MH_OFF + f * 384;
            int lo = 0, hi = 383;
            while (lo < hi) {
                int mid = (lo + hi) >> 1;
                if (uni[mb0 + mid] > u) hi = mid; else lo = mid + 1;
            }
            t3bin[t] = (uint32_t)lo;
            t_rib3[t] = u - (lo ? uni[mb0 + lo - 1] : 0u);
        }
        __syncthreads();

        // ---- tiny compact: 64 threads per feature ----
        {
            int f = t >> 6, i0 = t & 63;
            uint32_t c = umn(ccnt[f], (uint32_t)CANDCAP);
            uint32_t db[6], tb[6];
            #pragma unroll
            for (int j = 0; j < 6; ++j) { db[j] = dbk[f][j]; tb[j] = t3bin[f * 6 + j]; }
            for (uint32_t idx = (uint32_t)i0; idx < c; idx += 64) {
                uint32_t key = uni[f * CANDCAP + idx];
                uint32_t bin = key >> 20, sub = (key >> 14) & 63u;
                #pragma unroll
                for (int j = 0; j < 6; ++j) {
                    if (bin == db[j]) {
                        uint32_t mb2 = (uint32_t)j * 64u + sub;
                        #pragma unroll
                        for (int jj = 0; jj < 6; ++jj) {
                            if (mb2 == tb[jj]) {
                                uint32_t p = atomicAdd(&tcc[f * 6 + jj], 1u);
                                if (p < TCAP) uni[TC_OFF + (f * 6 + jj) * TCAP + p] = key;
                            }
                        }
                    }
                }
            }
        }
        __syncthreads();

        // ---- exact rank-count (16 lanes/task, 1536 slots over 2 rounds) ----
        #pragma unroll
        for (int rnd = 0; rnd < 2; ++rnd) {
            int idx = rnd * NTH + t;
            if (idx < NTASK * TCAP) {
                int task = idx >> 4, si = idx & 15;
                uint32_t c = umn(tcc[task], (uint32_t)TCAP);
                if ((uint32_t)si < c) {
                    uint32_t kk = uni[TC_OFF + task * TCAP + si];
                    uint32_t cl = 0;
                    for (uint32_t e = 0; e < c; ++e) {
                        uint32_t ke = uni[TC_OFF + task * TCAP + e];
                        cl += (ke < kk || (ke == kk && (int)e < si)) ? 1u : 0u;
                    }
                    uint32_t r3 = t_rib3[task];
                    if (cl == r3) t_res[task] = kk;
                    if ((uint32_t)si == c - 1 && r3 >= c) t_res[task] = kk;
                }
            }
        }
        __syncthreads();

        // ---- build pooled vector in LDS ----
        if (t < 16) {
            float nf = (float)n;
            float mean = s_sum[t] / nf;
            float varn = s_ssq[t] - s_sum[t] * s_sum[t] / nf;
            float denom = (float)(n >= 2 ? n - 1 : 1);
            float stdv = sqrtf(fmaxf(varn, 0.f) / denom);
            float qv[3];
            #pragma unroll
            for (int q = 0; q < 3; ++q) {
                float pos = 0.25f * (float)(q + 1) * (float)(n - 1);
                float frac = pos - floorf(pos);
                float lov = dec_key(t_res[t * 6 + 2 * q]);
                float hiv = dec_key(t_res[t * 6 + 2 * q + 1]);
                qv[q] = lov * (1.f - frac) + hiv * frac;
            }
            if (t == 0) pool[0] = nf;
            pool[1 + t] = mean;
            pool[17 + t] = qv[1];
            pool[33 + t] = dec_key(s_kmin[t]);
            pool[49 + t] = dec_key(s_kmax[t]);
            pool[65 + t] = stdv;
            pool[81 + t] = qv[0];
            pool[97 + t] = qv[2];
        }
    } else {
        if (t < 128) pool[t] = 0.f;
    }
    __syncthreads();

    // ---- fused MLP on wave 0: 113 -> 16 -> 4 -> 1 ----
    if (t < 64) {
        float h = (t < 16) ? b1[t] : 0.f;
        for (int i = 0; i < 113; ++i) {
            float pv = pool[i];
            if (t < 16) h += pv * W1[i * 16 + t];
        }
        if (t < 16) h = fmaxf(h, 0.f);
        float h2 = (t < 4) ? b2[t] : 0.f;
        #pragma unroll
        for (int j = 0; j < 16; ++j) {
            float hj = __shfl(h, j);
            if (t < 4) h2 += hj * W2[j * 4 + t];
        }
        if (t < 4) h2 = fmaxf(h2, 0.f);
        float o = 0.f;
        #pragma unroll
        for (int j = 0; j < 4; ++j) {
            float hj = __shfl(h2, j);
            o += hj * W3[j];
        }
        if (t == 0) out[b] = o + b3[0];
    }
}

extern "C" void kernel_launch(void* const* d_in, const int* in_sizes, int n_in,
                              void* d_out, int out_size, void* d_ws, size_t ws_size,
                              hipStream_t stream) {
    const float* inputs = (const float*)d_in[0];
    const unsigned char* mask = (const unsigned char*)d_in[1];
    const float* W1 = (const float*)d_in[2];
    const float* b1 = (const float*)d_in[3];
    const float* W2 = (const float*)d_in[4];
    const float* b2 = (const float*)d_in[5];
    const float* W3 = (const float*)d_in[6];
    const float* b3 = (const float*)d_in[7];
    float* out = (float*)d_out;

    fused_kernel<<<B_DIM, NTH, 0, stream>>>(inputs, mask, W1, b1, W2, b2, W3, b3, out);
}